// Round 7
// baseline (208.347 us; speedup 1.0000x reference)
//
#include <hip/hip_runtime.h>
#include <math.h>

typedef float v2 __attribute__((ext_vector_type(2)));

#define SCALE 1073741824.0   // 2^30 fixed-point for deterministic atomic sum
#define NPIX 12582912.0      // 16*3*512*512
#define C1f 1e-4f
#define C2f 9e-4f

struct Wts {
    float w[11];   // V-pass weights
    v2 hp[12];     // H-pass pair weights for element e=j+1: (w[j]|0, w[j-1]|0)
};

__device__ __forceinline__ v2 sp(float x) { v2 r; r.x = x; r.y = x; return r; }
__device__ __forceinline__ v2 f2(v2 a, v2 b, v2 c) {
    return __builtin_elementwise_fma(a, b, c);
}

__global__ __launch_bounds__(256, 2) void ssim_main(
    const float* __restrict__ img1, const float* __restrict__ img2,
    unsigned long long* __restrict__ acc, Wts W)
{
    __shared__ float red[4];
    const int tid = threadIdx.x;
    const int lane = tid & 63;
    const int wv = tid >> 6;
    const int r0 = blockIdx.x * 33;            // 16 strips of 33 output rows
    const int plane = blockIdx.y;              // 48 planes
    const int c = wv * 128 + 2 * lane;         // this thread's columns c, c+1

    const float* baseA = img1 + (size_t)plane * 262144;
    const float* baseB = img2 + (size_t)plane * 262144;

    // per-lane clamped chunk offsets (7 x float2 chunks covering [c-6, c+8))
    int off[7];
#pragma unroll
    for (int k = 0; k < 7; ++k) {
        int o = c - 6 + 2 * k;
        off[k] = o < 0 ? 0 : (o > 510 ? 510 : o);
    }
    // per-lane H weight pairs, zeroed where the element column is out of image
    v2 hpl[12];
#pragma unroll
    for (int j = 0; j < 12; ++j) {
        const int col = c - 5 + j;
        hpl[j] = (col >= 0 && col < 512) ? W.hp[j] : sp(0.f);
    }

    v2 rS[11], rD[11], rP[11], rM[11];         // ring: blurred u, v, u^2, v^2
    v2 A0[7], B0[7], A1[7], B1[7];             // parity prefetch buffers
    v2 loc = sp(0.f);

    // LOAD into an explicitly-named buffer (never a selected pointer!)
    auto LOAD = [&](v2 (&A)[7], v2 (&B)[7], int gr) {
        const int rc = gr < 0 ? 0 : (gr > 511 ? 511 : gr);
        const float* ra = baseA + rc * 512;
        const float* rb = baseB + rc * 512;
#pragma unroll
        for (int k = 0; k < 7; ++k) {
            A[k] = *(const v2*)(ra + off[k]);
            B[k] = *(const v2*)(rb + off[k]);
        }
    };
    auto HP = [&](v2 (&A)[7], v2 (&B)[7], int p, float m) {
        v2 hS = sp(0.f), hD = sp(0.f), hP = sp(0.f), hM = sp(0.f);
#pragma unroll
        for (int j = 0; j < 12; ++j) {
            const int e = j + 1;               // element col = c - 6 + e
            const float xa = (e & 1) ? A[e >> 1].y : A[e >> 1].x;
            const float xb = (e & 1) ? B[e >> 1].y : B[e >> 1].x;
            const float u = xa + xb, v = xa - xb;
            hS = f2(hpl[j], sp(u), hS);
            hD = f2(hpl[j], sp(v), hD);
            hP = f2(hpl[j], sp(u * u), hP);
            hM = f2(hpl[j], sp(v * v), hM);
        }
        const v2 mm = sp(m);                   // row-validity mask (0 or 1)
        rS[p] = hS * mm; rD[p] = hD * mm; rP[p] = hP * mm; rM[p] = hM * mm;
    };
    auto VOUT = [&](int p, float vm) {         // p compile-time at each site
        v2 S = sp(0.f), D = sp(0.f), P = sp(0.f), M = sp(0.f);
#pragma unroll
        for (int k = 0; k < 11; ++k) {
            const int q = (p + k) % 11;        // constant after unroll
            const v2 wk = sp(W.w[k]);
            S = f2(wk, rS[q], S);
            D = f2(wk, rD[q], D);
            P = f2(wk, rP[q], P);
            M = f2(wk, rM[q], M);
        }
        const v2 ss = S * S, dd = D * D;
        const v2 mu12  = (ss - dd) * sp(0.25f);
        const v2 musq  = (ss + dd) * sp(0.5f);
        const v2 sig12 = (P - M) * sp(0.25f) - mu12;
        const v2 sigsm = (P + M) * sp(0.5f) - musq;
        const v2 num = (sp(2.f) * mu12 + sp(C1f)) * (sp(2.f) * sig12 + sp(C2f));
        const v2 den = (musq + sp(C1f)) * (sigsm + sp(C2f));
        v2 r;
        r.x = __builtin_amdgcn_rcpf(den.x);
        r.y = __builtin_amdgcn_rcpf(den.y);
        r = r * (sp(2.f) - den * r);           // one NR step
        loc = f2(num * sp(vm), r, loc);        // vm: output-row validity mask
    };

    // ---- distance-2 pipelined sliding window over rows r0-5 .. r0+38 ------
    // step t (t=0..43): VOUT of output row r0+t-11 (t>=11), HP of row
    // gr(t)=r0-5+t from buf[t&1], then refill buf[t&1] with row gr(t+2).
    LOAD(A0, B0, r0 - 5);                      // preload rows t=0,1
    LOAD(A1, B1, r0 - 4);
#pragma unroll
    for (int t = 0; t < 44; ++t) {
        if (t >= 11) {
            const float vm = (r0 + t - 11 < 512) ? 1.f : 0.f;
            VOUT(t % 11, vm);
        }
        if (t < 43) {                          // last HP (t=43) is never read
            const int gr = r0 - 5 + t;
            const float m = (gr >= 0 && gr < 512) ? 1.f : 0.f;
            if (t & 1) HP(A1, B1, t % 11, m);
            else       HP(A0, B0, t % 11, m);
        }
        if (t <= 41) {                         // prefetch row t+2
            const int gn = r0 - 3 + t;
            if (t & 1) LOAD(A1, B1, gn);
            else       LOAD(A0, B0, gn);
        }
    }

    // ---- reduction -> fixed-point global atomic ----
    float l = loc.x + loc.y;
#pragma unroll
    for (int o2 = 32; o2; o2 >>= 1)
        l += __shfl_down(l, o2, 64);
    if (lane == 0) red[wv] = l;
    __syncthreads();
    if (tid == 0) {
        const float bs = red[0] + red[1] + red[2] + red[3];
        const unsigned long long q =
            (unsigned long long)__double2ll_rn((double)bs * SCALE);
        atomicAdd(acc, q);
    }
}

__global__ void ssim_final(const unsigned long long* __restrict__ acc,
                           float* __restrict__ out)
{
    if (threadIdx.x == 0)
        out[0] = (float)((double)(*acc) * (1.0 / SCALE) / NPIX);
}

extern "C" void kernel_launch(void* const* d_in, const int* in_sizes, int n_in,
                              void* d_out, int out_size, void* d_ws, size_t ws_size,
                              hipStream_t stream) {
    const float* img1 = (const float*)d_in[0];
    const float* img2 = (const float*)d_in[1];
    float* out = (float*)d_out;
    unsigned long long* acc = (unsigned long long*)d_ws;

    double g[11], ssum = 0.0;
    for (int i = 0; i < 11; ++i) {
        const double d = (double)(i - 5);
        g[i] = exp(-(d * d) / 4.5);
        ssum += g[i];
    }
    Wts W;
    for (int i = 0; i < 11; ++i) W.w[i] = (float)(g[i] / ssum);
    for (int j = 0; j < 12; ++j) {
        v2 p;
        p.x = (j <= 10) ? W.w[j] : 0.f;      // out0 weight for element j+1
        p.y = (j >= 1) ? W.w[j - 1] : 0.f;   // out1 weight for element j+1
        W.hp[j] = p;
    }

    hipMemsetAsync(d_ws, 0, sizeof(unsigned long long), stream);
    ssim_main<<<dim3(16, 48), 256, 0, stream>>>(img1, img2, acc, W);
    ssim_final<<<1, 64, 0, stream>>>(acc, out);
}

// Round 8
// 84.356 us; speedup vs baseline: 2.4699x; 2.4699x over previous
//
#include <hip/hip_runtime.h>
#include <math.h>

typedef float v2 __attribute__((ext_vector_type(2)));

#define SCALE 1073741824.0   // 2^30 fixed-point for deterministic atomic sum
#define NPIX 12582912.0      // 16*3*512*512
#define C1f 1e-4f
#define C2f 9e-4f

struct Wts {
    float w[11];   // V-pass weights
    v2 hp[12];     // H-pass pair weights for element e=j+1: (w[j]|0, w[j-1]|0)
};

__device__ __forceinline__ v2 sp(float x) { v2 r; r.x = x; r.y = x; return r; }
__device__ __forceinline__ v2 f2(v2 a, v2 b, v2 c) {
    return __builtin_elementwise_fma(a, b, c);
}

// ---- step macros: literal phase PH (ring slot) and parity-named buffers ----
// LOADP: clamped, always-legal row load into explicitly named buffers.
#define LOADP(Abuf, Bbuf, grow) do {                                        \
    int rc_ = (grow); rc_ = rc_ < 0 ? 0 : (rc_ > 511 ? 511 : rc_);          \
    const float* ra_ = baseA + rc_ * 512;                                   \
    const float* rb_ = baseB + rc_ * 512;                                   \
    _Pragma("unroll") for (int k_ = 0; k_ < 7; ++k_) {                      \
        Abuf[k_] = *(const v2*)(ra_ + off[k_]);                             \
        Bbuf[k_] = *(const v2*)(rb_ + off[k_]);                             \
    } } while (0)

// HPM: horizontal blur of one source row into ring slot PH (literal).
#define HPM(Abuf, Bbuf, PH, mval) do {                                      \
    v2 hS_ = sp(0.f), hD_ = sp(0.f), hP_ = sp(0.f), hM_ = sp(0.f);          \
    _Pragma("unroll") for (int j_ = 0; j_ < 12; ++j_) {                     \
        const int e_ = j_ + 1;                                              \
        const float xa_ = (e_ & 1) ? Abuf[e_ >> 1].y : Abuf[e_ >> 1].x;     \
        const float xb_ = (e_ & 1) ? Bbuf[e_ >> 1].y : Bbuf[e_ >> 1].x;     \
        const float u_ = xa_ + xb_, v_ = xa_ - xb_;                         \
        hS_ = f2(hpl[j_], sp(u_), hS_);                                     \
        hD_ = f2(hpl[j_], sp(v_), hD_);                                     \
        hP_ = f2(hpl[j_], sp(u_ * u_), hP_);                                \
        hM_ = f2(hpl[j_], sp(v_ * v_), hM_);                                \
    }                                                                       \
    const v2 mm_ = sp(mval);                                                \
    rS[PH] = hS_ * mm_; rD[PH] = hD_ * mm_;                                 \
    rP[PH] = hP_ * mm_; rM[PH] = hM_ * mm_; } while (0)

// VOUTM: vertical blur + SSIM for output row X-6; ring window is the 11
// slots (PH+1..PH+11)%12 (slot PH is the dead slot, overwritten right after).
#define VOUTM(PH, vmval) do {                                               \
    v2 S_ = sp(0.f), D_ = sp(0.f), P_ = sp(0.f), M_ = sp(0.f);              \
    _Pragma("unroll") for (int k_ = 0; k_ < 11; ++k_) {                     \
        const int q_ = ((PH) + 1 + k_) % 12;                                \
        const v2 wk_ = sp(W.w[k_]);                                         \
        S_ = f2(wk_, rS[q_], S_); D_ = f2(wk_, rD[q_], D_);                 \
        P_ = f2(wk_, rP[q_], P_); M_ = f2(wk_, rM[q_], M_);                 \
    }                                                                       \
    const v2 ss_ = S_ * S_, dd_ = D_ * D_;                                  \
    const v2 mu12_  = (ss_ - dd_) * sp(0.25f);                              \
    const v2 musq_  = (ss_ + dd_) * sp(0.5f);                               \
    const v2 sig12_ = (P_ - M_) * sp(0.25f) - mu12_;                        \
    const v2 sigsm_ = (P_ + M_) * sp(0.5f) - musq_;                         \
    const v2 num_ = (sp(2.f) * mu12_ + sp(C1f)) * (sp(2.f) * sig12_ + sp(C2f)); \
    const v2 den_ = (musq_ + sp(C1f)) * (sigsm_ + sp(C2f));                 \
    v2 r_;                                                                  \
    r_.x = __builtin_amdgcn_rcpf(den_.x);                                   \
    r_.y = __builtin_amdgcn_rcpf(den_.y);                                   \
    r_ = r_ * (sp(2.f) - den_ * r_);                                        \
    loc = f2(num_ * sp(vmval), r_, loc); } while (0)

// Prologue step: HP row X from buf[PAR], reload buf[PAR] with row X+2.
#define PSTEP(PH, PAR) do {                                                 \
    const float m_ = (X >= 0 && X < 512) ? 1.f : 0.f;                       \
    if (PAR) { HPM(A1, B1, PH, m_); LOADP(A1, B1, X + 2); }                 \
    else     { HPM(A0, B0, PH, m_); LOADP(A0, B0, X + 2); }                 \
    ++X;                                                                    \
    __builtin_amdgcn_sched_barrier(0); } while (0)

// Main step: VOUT(output X-6), then HP row X, then prefetch row X+2.
#define MSTEP(PH, PAR) do {                                                 \
    const float vm_ = (X - 6 < 512) ? 1.f : 0.f;                            \
    VOUTM(PH, vm_);                                                         \
    const float m_ = (X < 512) ? 1.f : 0.f;                                 \
    if (PAR) { HPM(A1, B1, PH, m_); LOADP(A1, B1, X + 2); }                 \
    else     { HPM(A0, B0, PH, m_); LOADP(A0, B0, X + 2); }                 \
    ++X;                                                                    \
    __builtin_amdgcn_sched_barrier(0); } while (0)

__global__ __launch_bounds__(256, 2) void ssim_main(
    const float* __restrict__ img1, const float* __restrict__ img2,
    unsigned long long* __restrict__ acc, Wts W)
{
    __shared__ float red[4];
    const int tid = threadIdx.x;
    const int lane = tid & 63;
    const int wv = tid >> 6;
    const int r0 = blockIdx.x * 48;            // 11 strips of 48 output rows
    const int plane = blockIdx.y;              // 48 planes
    const int c = wv * 128 + 2 * lane;         // this thread's columns c, c+1

    const float* baseA = img1 + (size_t)plane * 262144;
    const float* baseB = img2 + (size_t)plane * 262144;

    // per-lane clamped chunk offsets (7 x float2 chunks covering [c-6, c+8))
    int off[7];
#pragma unroll
    for (int k = 0; k < 7; ++k) {
        int o = c - 6 + 2 * k;
        off[k] = o < 0 ? 0 : (o > 510 ? 510 : o);
    }
    // per-lane H weight pairs, zeroed where the element column is out of image
    v2 hpl[12];
#pragma unroll
    for (int j = 0; j < 12; ++j) {
        const int col = c - 5 + j;
        hpl[j] = (col >= 0 && col < 512) ? W.hp[j] : sp(0.f);
    }

    v2 rS[12], rD[12], rP[12], rM[12];         // 12-slot ring (period 12)
    v2 A0[7], B0[7], A1[7], B1[7];             // parity row buffers
    v2 loc = sp(0.f);

    int X = r0 - 5;                            // row being pushed this step
    LOADP(A0, B0, r0 - 5);                     // preload rows for t=0,1
    LOADP(A1, B1, r0 - 4);
    __builtin_amdgcn_sched_barrier(0);

    // ---- prologue: steps t=0..10 fill ring slots 0..10 ----
    PSTEP(0, 0);  PSTEP(1, 1);  PSTEP(2, 0);  PSTEP(3, 1);
    PSTEP(4, 0);  PSTEP(5, 1);  PSTEP(6, 0);  PSTEP(7, 1);
    PSTEP(8, 0);  PSTEP(9, 1);  PSTEP(10, 0);

    // ---- main: 48 steps (t=11..58) as 4 x 12-step bodies; phases repeat ----
    for (int b = 0; b < 4; ++b) {
        MSTEP(11, 1); MSTEP(0, 0);  MSTEP(1, 1);  MSTEP(2, 0);
        MSTEP(3, 1);  MSTEP(4, 0);  MSTEP(5, 1);  MSTEP(6, 0);
        MSTEP(7, 1);  MSTEP(8, 0);  MSTEP(9, 1);  MSTEP(10, 0);
    }

    // ---- reduction -> fixed-point global atomic ----
    float l = loc.x + loc.y;
#pragma unroll
    for (int o2 = 32; o2; o2 >>= 1)
        l += __shfl_down(l, o2, 64);
    if (lane == 0) red[wv] = l;
    __syncthreads();
    if (tid == 0) {
        const float bs = red[0] + red[1] + red[2] + red[3];
        const unsigned long long q =
            (unsigned long long)__double2ll_rn((double)bs * SCALE);
        atomicAdd(acc, q);
    }
}

__global__ void ssim_final(const unsigned long long* __restrict__ acc,
                           float* __restrict__ out)
{
    if (threadIdx.x == 0)
        out[0] = (float)((double)(*acc) * (1.0 / SCALE) / NPIX);
}

extern "C" void kernel_launch(void* const* d_in, const int* in_sizes, int n_in,
                              void* d_out, int out_size, void* d_ws, size_t ws_size,
                              hipStream_t stream) {
    const float* img1 = (const float*)d_in[0];
    const float* img2 = (const float*)d_in[1];
    float* out = (float*)d_out;
    unsigned long long* acc = (unsigned long long*)d_ws;

    double g[11], ssum = 0.0;
    for (int i = 0; i < 11; ++i) {
        const double d = (double)(i - 5);
        g[i] = exp(-(d * d) / 4.5);
        ssum += g[i];
    }
    Wts W;
    for (int i = 0; i < 11; ++i) W.w[i] = (float)(g[i] / ssum);
    for (int j = 0; j < 12; ++j) {
        v2 p;
        p.x = (j <= 10) ? W.w[j] : 0.f;      // out0 weight for element j+1
        p.y = (j >= 1) ? W.w[j - 1] : 0.f;   // out1 weight for element j+1
        W.hp[j] = p;
    }

    hipMemsetAsync(d_ws, 0, sizeof(unsigned long long), stream);
    ssim_main<<<dim3(11, 48), 256, 0, stream>>>(img1, img2, acc, W);
    ssim_final<<<1, 64, 0, stream>>>(acc, out);
}